// Round 1
// baseline (326.384 us; speedup 1.0000x reference)
//
#include <hip/hip_runtime.h>
#include <cstdint>
#include <cstddef>

// Problem constants
static constexpr int N1 = 40000;
static constexpr int N2 = 10000;
static constexpr int KNN = 16;
static constexpr float EPS = 1e-5f;

// Workspace layout (float offsets)
static constexpr size_t OFF_X1H = 0;          // N1*64 (y1 then x1h in-place)
static constexpr size_t OFF_X2H = 2560000;    // N2*64
static constexpr size_t OFF_X2I = 3200000;    // N1*64
static constexpr size_t OFF_XQ  = 5760000;    // N1*64
static constexpr size_t OFF_XK  = 8320000;    // N1*64
static constexpr size_t OFF_XV  = 10880000;   // N1*64 (PERMUTED: [j][d*8+s])
static constexpr size_t OFF_W1B = 13440000;   // N1*KNN*8
static constexpr size_t OFF_ST  = 18560000;   // 512 floats of stats:
// st1 = +0   (sum[64], sumsq[64])
// st2 = +128
// st0 = +256
// stw1= +384 (sum[8], sumsq[8])

// ---------------------------------------------------------------------------
// Generic GEMM: Y[N,64] = X[N,CIN] @ W[CIN,64] + B ; optional channel permute
// block = 256 threads, tile = (16*RPT) rows x 64 cols, thread = RPT rows x 4 cols
// ---------------------------------------------------------------------------
template<int CIN, int RPT, bool PERM>
__global__ __launch_bounds__(256) void gemm_k(const float* __restrict__ X,
                                              const float* __restrict__ W,
                                              const float* __restrict__ B,
                                              float* __restrict__ Y, int N)
{
    constexpr int ROWS = 16 * RPT;
    __shared__ float Ws[CIN * 64];
    __shared__ float Xs[ROWS][CIN + 1];

    for (int t = threadIdx.x; t < CIN * 64; t += 256) Ws[t] = W[t];

    const int base = blockIdx.x * ROWS;
    // load X tile (guarded), float4 granularity
    for (int f = threadIdx.x; f < ROWS * CIN / 4; f += 256) {
        int e = f * 4;
        int r = e / CIN;
        int col = e % CIN;
        int grow = base + r;
        float4 v = make_float4(0.f, 0.f, 0.f, 0.f);
        if (grow < N) v = *(const float4*)(X + (size_t)grow * CIN + col);
        Xs[r][col + 0] = v.x; Xs[r][col + 1] = v.y;
        Xs[r][col + 2] = v.z; Xs[r][col + 3] = v.w;
    }
    __syncthreads();

    const int cg = threadIdx.x & 15;   // columns cg*4 .. cg*4+3
    const int rg = threadIdx.x >> 4;   // rows rg*RPT .. rg*RPT+RPT-1
    float4 bv = *(const float4*)(B + cg * 4);
    float acc[RPT][4];
#pragma unroll
    for (int j = 0; j < RPT; j++) {
        acc[j][0] = bv.x; acc[j][1] = bv.y; acc[j][2] = bv.z; acc[j][3] = bv.w;
    }

#pragma unroll 8
    for (int k = 0; k < CIN; k++) {
        float4 w4 = *(const float4*)&Ws[k * 64 + cg * 4];
#pragma unroll
        for (int j = 0; j < RPT; j++) {
            float x = Xs[rg * RPT + j][k];
            acc[j][0] += x * w4.x; acc[j][1] += x * w4.y;
            acc[j][2] += x * w4.z; acc[j][3] += x * w4.w;
        }
    }

#pragma unroll
    for (int j = 0; j < RPT; j++) {
        int r = base + rg * RPT + j;
        if (r < N) {
            if (PERM) {
#pragma unroll
                for (int m = 0; m < 4; m++) {
                    int c = cg * 4 + m;
                    int pc = (c & 7) * 8 + (c >> 3); // [s*8+d] -> [d*8+s]
                    Y[(size_t)r * 64 + pc] = acc[j][m];
                }
            } else {
                *(float4*)(Y + (size_t)r * 64 + cg * 4) =
                    make_float4(acc[j][0], acc[j][1], acc[j][2], acc[j][3]);
            }
        }
    }
}

// ---------------------------------------------------------------------------
// Per-channel (64) sum & sumsq over rows of Y[N,64] -> atomicAdd into stats
// ---------------------------------------------------------------------------
__global__ __launch_bounds__(256) void colstats_k(const float* __restrict__ Y,
                                                  int N, float* __restrict__ stats)
{
    const int c = threadIdx.x & 63;
    const int rg = threadIdx.x >> 6;
    float s = 0.f, s2 = 0.f;
    for (int i = blockIdx.x * 4 + rg; i < N; i += gridDim.x * 4) {
        float v = Y[(size_t)i * 64 + c];
        s += v; s2 += v * v;
    }
    __shared__ float red[256];
    red[threadIdx.x] = s; __syncthreads();
    if (threadIdx.x < 64)
        atomicAdd(&stats[c], red[c] + red[64 + c] + red[128 + c] + red[192 + c]);
    __syncthreads();
    red[threadIdx.x] = s2; __syncthreads();
    if (threadIdx.x < 64)
        atomicAdd(&stats[64 + c], red[c] + red[64 + c] + red[128 + c] + red[192 + c]);
}

// ---------------------------------------------------------------------------
// In-place BN (training) + ReLU on Y[N,64]
// ---------------------------------------------------------------------------
__global__ __launch_bounds__(256) void bnrelu_k(float* __restrict__ Y,
                                                const float* __restrict__ stats,
                                                const float* __restrict__ g,
                                                const float* __restrict__ beta,
                                                int total, float invN)
{
    __shared__ float sc[64], sh[64];
    if (threadIdx.x < 64) {
        float mean = stats[threadIdx.x] * invN;
        float var = stats[64 + threadIdx.x] * invN - mean * mean;
        float s = g[threadIdx.x] * rsqrtf(var + EPS);
        sc[threadIdx.x] = s;
        sh[threadIdx.x] = beta[threadIdx.x] - mean * s;
    }
    __syncthreads();
    int idx = blockIdx.x * 256 + threadIdx.x;
    if (idx < total) {
        int c = idx & 63;
        float v = Y[idx] * sc[c] + sh[c];
        Y[idx] = v > 0.f ? v : 0.f;
    }
}

// ---------------------------------------------------------------------------
// 3-NN inverse-distance interpolation: x2i[i,c] = sum_k w_k * x2h[idx[i,k],c]
// one 64-lane row-group per node, 4 nodes per block
// ---------------------------------------------------------------------------
__global__ __launch_bounds__(256) void interp_k(const float* __restrict__ p1,
                                                const float* __restrict__ p2,
                                                const int* __restrict__ iidx,
                                                const float* __restrict__ x2h,
                                                float* __restrict__ x2i)
{
    const int i = blockIdx.x * 4 + (threadIdx.x >> 6);
    const int c = threadIdx.x & 63;
    int j0 = iidx[i * 3 + 0], j1 = iidx[i * 3 + 1], j2 = iidx[i * 3 + 2];
    float ax = p1[i * 3 + 0], ay = p1[i * 3 + 1], az = p1[i * 3 + 2];
    float dx, dy, dz;
    dx = ax - p2[j0 * 3 + 0]; dy = ay - p2[j0 * 3 + 1]; dz = az - p2[j0 * 3 + 2];
    float w0 = 1.f / (sqrtf(dx * dx + dy * dy + dz * dz) + 1e-8f);
    dx = ax - p2[j1 * 3 + 0]; dy = ay - p2[j1 * 3 + 1]; dz = az - p2[j1 * 3 + 2];
    float w1 = 1.f / (sqrtf(dx * dx + dy * dy + dz * dz) + 1e-8f);
    dx = ax - p2[j2 * 3 + 0]; dy = ay - p2[j2 * 3 + 1]; dz = az - p2[j2 * 3 + 2];
    float w2 = 1.f / (sqrtf(dx * dx + dy * dy + dz * dz) + 1e-8f);
    float inv = 1.f / (w0 + w1 + w2);
    x2i[(size_t)i * 64 + c] = inv * (w0 * x2h[(size_t)j0 * 64 + c] +
                                     w1 * x2h[(size_t)j1 * 64 + c] +
                                     w2 * x2h[(size_t)j2 * 64 + c]);
}

// ---------------------------------------------------------------------------
// Stats of w = xk[knn[i,k]] - xq[i] over (i,k), per channel (64)
// ---------------------------------------------------------------------------
__global__ __launch_bounds__(256) void wstats_k(const float* __restrict__ xq,
                                                const float* __restrict__ xk,
                                                const int* __restrict__ knn,
                                                float* __restrict__ stats0)
{
    const int c = threadIdx.x & 63;
    const int rg = threadIdx.x >> 6;
    float s = 0.f, s2 = 0.f;
    for (int i = blockIdx.x * 4 + rg; i < N1; i += gridDim.x * 4) {
        float q = xq[(size_t)i * 64 + c];
#pragma unroll
        for (int k = 0; k < KNN; k++) {
            int j = knn[i * KNN + k];
            float w = xk[(size_t)j * 64 + c] - q;
            s += w; s2 += w * w;
        }
    }
    __shared__ float red[256];
    red[threadIdx.x] = s; __syncthreads();
    if (threadIdx.x < 64)
        atomicAdd(&stats0[c], red[c] + red[64 + c] + red[128 + c] + red[192 + c]);
    __syncthreads();
    red[threadIdx.x] = s2; __syncthreads();
    if (threadIdx.x < 64)
        atomicAdd(&stats0[64 + c], red[c] + red[64 + c] + red[128 + c] + red[192 + c]);
}

// ---------------------------------------------------------------------------
// w1 = relu(bn0(xk_g - xq)) @ Ww1 + bw1  -> w1buf[(i*16+k)*8 + d]
// also accumulates per-d sum/sumsq of w1 into statsw1
// 8-lane group per node, lane l8 owns channels 8*l8..8*l8+7 and output d=l8
// grid MUST be N1/32 blocks (exact) — no guards, uniform __syncthreads
// ---------------------------------------------------------------------------
__global__ __launch_bounds__(256) void wmlp1_k(const float* __restrict__ xq,
                                               const float* __restrict__ xk,
                                               const int* __restrict__ knn,
                                               const float* __restrict__ stats0,
                                               const float* __restrict__ gw0,
                                               const float* __restrict__ bw0,
                                               const float* __restrict__ Ww1,
                                               const float* __restrict__ bw1,
                                               float* __restrict__ w1buf,
                                               float* __restrict__ statsw1)
{
    const int l8 = threadIdx.x & 7;
    const int grp = threadIdx.x >> 3;          // 0..31
    const int i = blockIdx.x * 32 + grp;       // exact: 1250*32 = 40000
    const float cinv = 1.f / (float)(N1 * KNN);

    float sc0[8], sh0[8];
#pragma unroll
    for (int m = 0; m < 8; m++) {
        int ch = l8 * 8 + m;
        float mean = stats0[ch] * cinv;
        float var = stats0[64 + ch] * cinv - mean * mean;
        float s = gw0[ch] * rsqrtf(var + EPS);
        sc0[m] = s; sh0[m] = bw0[ch] - mean * s;
    }
    float wW[8][8];
#pragma unroll
    for (int m = 0; m < 8; m++)
#pragma unroll
        for (int d = 0; d < 8; d++) wW[m][d] = Ww1[(l8 * 8 + m) * 8 + d];
    float bias[8];
#pragma unroll
    for (int d = 0; d < 8; d++) bias[d] = bw1[d];

    float qr[8];
    *(float4*)&qr[0] = *(const float4*)(xq + (size_t)i * 64 + l8 * 8);
    *(float4*)&qr[4] = *(const float4*)(xq + (size_t)i * 64 + l8 * 8 + 4);

    float sacc[8], s2acc[8];
#pragma unroll
    for (int d = 0; d < 8; d++) { sacc[d] = 0.f; s2acc[d] = 0.f; }

    for (int k = 0; k < KNN; k++) {
        int j = knn[i * KNN + k];
        float kr[8];
        *(float4*)&kr[0] = *(const float4*)(xk + (size_t)j * 64 + l8 * 8);
        *(float4*)&kr[4] = *(const float4*)(xk + (size_t)j * 64 + l8 * 8 + 4);
        float p[8];
#pragma unroll
        for (int d = 0; d < 8; d++) p[d] = 0.f;
#pragma unroll
        for (int m = 0; m < 8; m++) {
            float u = (kr[m] - qr[m]) * sc0[m] + sh0[m];
            u = u > 0.f ? u : 0.f;
#pragma unroll
            for (int d = 0; d < 8; d++) p[d] += u * wW[m][d];
        }
        // butterfly reduce across the 8-lane group
#pragma unroll
        for (int d = 0; d < 8; d++) p[d] += __shfl_xor(p[d], 1);
#pragma unroll
        for (int d = 0; d < 8; d++) p[d] += __shfl_xor(p[d], 2);
#pragma unroll
        for (int d = 0; d < 8; d++) p[d] += __shfl_xor(p[d], 4);
#pragma unroll
        for (int d = 0; d < 8; d++) {
            p[d] += bias[d];
            sacc[d] += p[d];
            s2acc[d] += p[d] * p[d];
        }
        if (l8 == 0) {
            float* wp = w1buf + ((size_t)i * KNN + k) * 8;
            *(float4*)wp = make_float4(p[0], p[1], p[2], p[3]);
            *(float4*)(wp + 4) = make_float4(p[4], p[5], p[6], p[7]);
        }
    }

    // block-reduce statsw1 (only one lane per group contributes)
    __shared__ float red[32][16];
    if (l8 == 0) {
#pragma unroll
        for (int d = 0; d < 8; d++) { red[grp][d] = sacc[d]; red[grp][8 + d] = s2acc[d]; }
    }
    __syncthreads();
    if (threadIdx.x < 16) {
        float s = 0.f;
        for (int g = 0; g < 32; g++) s += red[g][threadIdx.x];
        atomicAdd(&statsw1[threadIdx.x], s);
    }
}

// ---------------------------------------------------------------------------
// Final: v1 = relu(bn1(w1)); w2 = v1 @ Ww2 + bw2; softmax over k;
// aggregate with permuted xv; out = x1h + agg
// 8-lane group per node; lane l8 = plane d; grid exact N1/32 blocks
// ---------------------------------------------------------------------------
__global__ __launch_bounds__(256) void attn_k(const float* __restrict__ w1buf,
                                              const float* __restrict__ statsw1,
                                              const float* __restrict__ gw1,
                                              const float* __restrict__ bew1,
                                              const float* __restrict__ Ww2,
                                              const float* __restrict__ bw2,
                                              const int* __restrict__ knn,
                                              const float* __restrict__ xvp,
                                              const float* __restrict__ x1h,
                                              float* __restrict__ out)
{
    const int l8 = threadIdx.x & 7;
    const int grp8 = (threadIdx.x >> 3) & 7;
    const int wave = threadIdx.x >> 6;
    const int i = blockIdx.x * 32 + wave * 8 + grp8;
    const float cinv = 1.f / (float)(N1 * KNN);

    float sc1[8], sh1[8];
#pragma unroll
    for (int e = 0; e < 8; e++) {
        float mean = statsw1[e] * cinv;
        float var = statsw1[8 + e] * cinv - mean * mean;
        float s = gw1[e] * rsqrtf(var + EPS);
        sc1[e] = s; sh1[e] = bew1[e] - mean * s;
    }
    float w2c[8];
#pragma unroll
    for (int e = 0; e < 8; e++) w2c[e] = Ww2[e * 8 + l8];
    const float b2v = bw2[l8];

    float w2k[KNN];
#pragma unroll
    for (int k = 0; k < KNN; k++) {
        const float* wp = w1buf + ((size_t)i * KNN + k) * 8;
        float w1v[8];
        *(float4*)&w1v[0] = *(const float4*)wp;
        *(float4*)&w1v[4] = *(const float4*)(wp + 4);
        float a = b2v;
#pragma unroll
        for (int e = 0; e < 8; e++) {
            float v = w1v[e] * sc1[e] + sh1[e];
            v = v > 0.f ? v : 0.f;
            a += v * w2c[e];
        }
        w2k[k] = a;
    }
    // softmax over k (in registers)
    float mx = w2k[0];
#pragma unroll
    for (int k = 1; k < KNN; k++) mx = fmaxf(mx, w2k[k]);
    float sum = 0.f;
#pragma unroll
    for (int k = 0; k < KNN; k++) { w2k[k] = __expf(w2k[k] - mx); sum += w2k[k]; }
    const float inv = 1.f / sum;

    float4 acc0 = make_float4(0.f, 0.f, 0.f, 0.f);
    float4 acc1 = make_float4(0.f, 0.f, 0.f, 0.f);
#pragma unroll
    for (int k = 0; k < KNN; k++) {
        int j = knn[i * KNN + k];
        const float* vp = xvp + (size_t)j * 64 + l8 * 8;
        float4 v0 = *(const float4*)vp;
        float4 v1 = *(const float4*)(vp + 4);
        float wgt = w2k[k] * inv;
        acc0.x += v0.x * wgt; acc0.y += v0.y * wgt;
        acc0.z += v0.z * wgt; acc0.w += v0.w * wgt;
        acc1.x += v1.x * wgt; acc1.y += v1.y * wgt;
        acc1.z += v1.z * wgt; acc1.w += v1.w * wgt;
    }

    // transpose through LDS for coalesced epilogue (pad 65 to break conflicts)
    __shared__ float lds[4][8][65];
    float* Lp = &lds[wave][grp8][0];
    Lp[0 * 8 + l8] = acc0.x; Lp[1 * 8 + l8] = acc0.y;
    Lp[2 * 8 + l8] = acc0.z; Lp[3 * 8 + l8] = acc0.w;
    Lp[4 * 8 + l8] = acc1.x; Lp[5 * 8 + l8] = acc1.y;
    Lp[6 * 8 + l8] = acc1.z; Lp[7 * 8 + l8] = acc1.w;
    __syncthreads();

    const int lane = threadIdx.x & 63;
    const int ibase = blockIdx.x * 32 + wave * 8;
#pragma unroll
    for (int g = 0; g < 8; g++) {
        int r = ibase + g;
        out[(size_t)r * 64 + lane] = x1h[(size_t)r * 64 + lane] + lds[wave][g][lane];
    }
}

// ---------------------------------------------------------------------------
extern "C" void kernel_launch(void* const* d_in, const int* in_sizes, int n_in,
                              void* d_out, int out_size, void* d_ws, size_t ws_size,
                              hipStream_t stream)
{
    const float* p1   = (const float*)d_in[0];
    const float* x1   = (const float*)d_in[1];
    const float* p2   = (const float*)d_in[2];
    const float* x2   = (const float*)d_in[3];
    const int*   knn  = (const int*)d_in[4];
    const int*   iidx = (const int*)d_in[5];
    const float* W1   = (const float*)d_in[6];
    const float* b1   = (const float*)d_in[7];
    const float* g1   = (const float*)d_in[8];
    const float* be1  = (const float*)d_in[9];
    const float* W2   = (const float*)d_in[10];
    const float* b2   = (const float*)d_in[11];
    const float* g2   = (const float*)d_in[12];
    const float* be2  = (const float*)d_in[13];
    const float* Wq   = (const float*)d_in[14];
    const float* bq   = (const float*)d_in[15];
    const float* Wk   = (const float*)d_in[16];
    const float* bk   = (const float*)d_in[17];
    const float* Wv   = (const float*)d_in[18];
    const float* bv   = (const float*)d_in[19];
    const float* gw0  = (const float*)d_in[20];
    const float* bw0  = (const float*)d_in[21];
    const float* Ww1  = (const float*)d_in[22];
    const float* bw1  = (const float*)d_in[23];
    const float* gw1  = (const float*)d_in[24];
    const float* bew1 = (const float*)d_in[25];
    const float* Ww2  = (const float*)d_in[26];
    const float* bw2  = (const float*)d_in[27];

    float* ws   = (float*)d_ws;
    float* x1h  = ws + OFF_X1H;
    float* x2h  = ws + OFF_X2H;
    float* x2i  = ws + OFF_X2I;
    float* xq   = ws + OFF_XQ;
    float* xk   = ws + OFF_XK;
    float* xv   = ws + OFF_XV;
    float* w1b  = ws + OFF_W1B;
    float* st1  = ws + OFF_ST;
    float* st2  = st1 + 128;
    float* st0  = st1 + 256;
    float* stw1 = st1 + 384;
    float* outp = (float*)d_out;

    // zero the stats region (atomics accumulate into it)
    hipMemsetAsync(st1, 0, 512 * sizeof(float), stream);

    // linear1: y1 = x1 @ W1 + b1
    gemm_k<64, 4, false><<<N1 / 64, 256, 0, stream>>>(x1, W1, b1, x1h, N1);
    colstats_k<<<512, 256, 0, stream>>>(x1h, N1, st1);
    // linear2: y2 = x2 @ W2 + b2
    gemm_k<128, 2, false><<<(N2 + 31) / 32, 256, 0, stream>>>(x2, W2, b2, x2h, N2);
    colstats_k<<<512, 256, 0, stream>>>(x2h, N2, st2);
    // BN+ReLU in place
    bnrelu_k<<<(N1 * 64) / 256, 256, 0, stream>>>(x1h, st1, g1, be1, N1 * 64, 1.f / N1);
    bnrelu_k<<<(N2 * 64) / 256, 256, 0, stream>>>(x2h, st2, g2, be2, N2 * 64, 1.f / N2);
    // 3-NN interpolation
    interp_k<<<N1 / 4, 256, 0, stream>>>(p1, p2, iidx, x2h, x2i);
    // q/k/v projections (v stored channel-permuted)
    gemm_k<64, 4, false><<<N1 / 64, 256, 0, stream>>>(x1h, Wq, bq, xq, N1);
    gemm_k<64, 4, false><<<N1 / 64, 256, 0, stream>>>(x2i, Wk, bk, xk, N1);
    gemm_k<64, 4, true ><<<N1 / 64, 256, 0, stream>>>(x2i, Wv, bv, xv, N1);
    // BN0 stats of w = xk_g - xq
    wstats_k<<<640, 256, 0, stream>>>(xq, xk, knn, st0);
    // w1 = relu(bn0(w)) @ Ww1 + bw1, + stats of w1
    wmlp1_k<<<N1 / 32, 256, 0, stream>>>(xq, xk, knn, st0, gw0, bw0, Ww1, bw1, w1b, stw1);
    // bn1 + relu + Ww2 + softmax + aggregation + residual
    attn_k<<<N1 / 32, 256, 0, stream>>>(w1b, stw1, gw1, bew1, Ww2, bw2, knn, xv, x1h, outp);
}